// Round 4
// baseline (257.385 us; speedup 1.0000x reference)
//
#include <hip/hip_runtime.h>

#define B_ 2
#define T_ 4096
#define E_ 768
#define H_ 12
#define S_ 64
#define WIN_ 256

typedef unsigned short u16;
typedef unsigned int u32;
typedef __attribute__((ext_vector_type(8))) short bf16x8;
typedef __attribute__((ext_vector_type(4))) short bf16x4;
typedef __attribute__((ext_vector_type(4))) float f32x4;

__device__ __forceinline__ u16 f2bf(float f) {
  u32 u = __float_as_uint(f);
  u += ((u >> 16) & 1u) + 0x7fffu;   // RNE
  return (u16)(u >> 16);
}

// ---------------- fp32 -> bf16, all 4 tensors in one dispatch ----------------
__global__ void cvt_all(const float* __restrict__ x, const float* __restrict__ wq,
                        const float* __restrict__ wk, const float* __restrict__ wv,
                        u16* __restrict__ xb, u16* __restrict__ wb) {
  const int n4x = B_ * T_ * E_ / 4;
  const int n4w = E_ * E_ / 4;
  int i = blockIdx.x * 256 + threadIdx.x;
  const float* src;
  u16* dst;
  int j;
  if (i < n4x) {
    src = x; dst = xb; j = i;
  } else {
    int t = i - n4x;
    int z = t / n4w;
    if (z >= 3) return;
    j = t - z * n4w;
    src = (z == 0) ? wq : ((z == 1) ? wk : wv);
    dst = wb + (size_t)z * E_ * E_;
  }
  float4 v = ((const float4*)src)[j];
  ushort4 o;
  o.x = f2bf(v.x); o.y = f2bf(v.y); o.z = f2bf(v.z); o.w = f2bf(v.w);
  ((ushort4*)dst)[j] = o;
}

// ---------------- QKV projection GEMM: barrier-free, per-wave 64x64 tile ----------------
// A (12.6MB) lives in L3, W (1.2MB/matrix) hot in per-XCD L2 -> fragments read
// directly from global in MFMA A/B layout (16B/lane row fragments), 1-deep
// register prefetch, zero LDS, zero __syncthreads.
__global__ __launch_bounds__(256)
void gemm_qkv(const u16* __restrict__ xb, const u16* __restrict__ wb,
              u16* __restrict__ qkv) {
  const int M = B_ * T_;
  int tid = threadIdx.x;
  int lane = tid & 63, wave = tid >> 6;
  int q8 = lane >> 4, nl = lane & 15;
  int m0 = blockIdx.x * 256 + wave * 64;
  int n0 = blockIdx.y * 64;
  int z = blockIdx.z;
  const u16* A = xb;
  const u16* Bmat = wb + (size_t)z * E_ * E_;
  u16* C = qkv + (size_t)z * M * E_;
  float scale = (z == 0) ? (0.125f * 1.44269504088896f) : 1.0f;

  // fragment base pointers (advance by 32 elements per K-step)
  const u16* ap[4];
  const u16* bp[4];
#pragma unroll
  for (int i = 0; i < 4; ++i) {
    ap[i] = A + (size_t)(m0 + i * 16 + nl) * E_ + q8 * 8;
    bp[i] = Bmat + (size_t)(n0 + i * 16 + nl) * E_ + q8 * 8;
  }

  f32x4 acc[4][4] = {};
  bf16x8 af[2][4], bf[2][4];
  // prologue: k=0 into slot 0
#pragma unroll
  for (int i = 0; i < 4; ++i) { af[0][i] = *(const bf16x8*)ap[i]; bf[0][i] = *(const bf16x8*)bp[i]; }

  const int NK = E_ / 32;   // 24
#pragma unroll 2
  for (int ki = 0; ki < NK; ++ki) {
    int cur = ki & 1, nxt = cur ^ 1;
    if (ki + 1 < NK) {
      int ko = (ki + 1) * 32;
#pragma unroll
      for (int i = 0; i < 4; ++i) {
        af[nxt][i] = *(const bf16x8*)(ap[i] + ko);
        bf[nxt][i] = *(const bf16x8*)(bp[i] + ko);
      }
    }
#pragma unroll
    for (int i = 0; i < 4; ++i)
#pragma unroll
      for (int j = 0; j < 4; ++j)
        acc[i][j] = __builtin_amdgcn_mfma_f32_16x16x32_bf16(af[cur][i], bf[cur][j], acc[i][j], 0, 0, 0);
  }

#pragma unroll
  for (int i = 0; i < 4; ++i)
#pragma unroll
    for (int j = 0; j < 4; ++j)
#pragma unroll
      for (int r = 0; r < 4; ++r) {
        int row = m0 + i * 16 + q8 * 4 + r;
        int col = n0 + j * 16 + nl;
        C[(size_t)row * E_ + col] = f2bf(acc[i][j][r] * scale);
      }
}

// ---------------- V transpose: v[b*T+t][e] -> vT[b][e][t] ----------------
__global__ void transpose_v(const u16* __restrict__ v, u16* __restrict__ vT) {
  __shared__ u16 lt[64][66];
  int t = threadIdx.x;
  int t0 = blockIdx.x * 64;
  int e0 = blockIdx.y * 64;
  int b = blockIdx.z;
#pragma unroll
  for (int i = 0; i < 2; ++i) {
    int u = t + i * 256;
    int tok = u >> 3, cg = u & 7;
    bf16x8 val = *(const bf16x8*)(v + (size_t)(b * T_ + t0 + tok) * E_ + e0 + cg * 8);
#pragma unroll
    for (int j = 0; j < 8; ++j) lt[tok][cg * 8 + j] = (u16)val[j];
  }
  __syncthreads();
#pragma unroll
  for (int i = 0; i < 2; ++i) {
    int u = t + i * 256;
    int d = u >> 3, ck = u & 7;
    bf16x8 o;
#pragma unroll
    for (int j = 0; j < 8; ++j) o[j] = (short)lt[ck * 8 + j][d];
    *(bf16x8*)(vT + (size_t)(b * E_ + e0 + d) * T_ + t0 + ck * 8) = o;
  }
}

// ---------------- banded flash attention, barrier-free + register prefetch ----------------
__global__ __launch_bounds__(256)
void attn_kernel(const u16* __restrict__ qkv, const u16* __restrict__ vT,
                 float* __restrict__ out) {
  const int Mtot = B_ * T_;
  const u16* qb = qkv;
  const u16* kb = qkv + (size_t)Mtot * E_;

  __shared__ u16 Pl[4][2][16][36];

  int tid = threadIdx.x;
  int lane = tid & 63, wave = tid >> 6;
  int q8 = lane >> 4, nl = lane & 15;
  int qs = blockIdx.x * 128;
  int bh = blockIdx.y;
  int b = bh / H_, h = bh % H_;
  int qw = qs + wave * 32;
  size_t ho = (size_t)h * S_;

  bf16x8 aq[2][2];
#pragma unroll
  for (int mt = 0; mt < 2; ++mt) {
    const u16* qrow = qb + (size_t)(b * T_ + qw + mt * 16 + nl) * E_ + ho;
    aq[mt][0] = *(const bf16x8*)(qrow + q8 * 8);
    aq[mt][1] = *(const bf16x8*)(qrow + 32 + q8 * 8);
  }

  f32x4 O[2][4] = {};
  f32x4 lacc[2] = {};

  int klo = qw - WIN_; if (klo < 0) klo = 0;
  int khi = qw + 32 + WIN_; if (khi > T_) khi = T_;

  const u16* kbase = kb + (size_t)b * T_ * E_ + ho;
  const u16* vbase = vT + (size_t)b * E_ * T_ + ho * T_;

  bf16x8 bk[2][2];
#pragma unroll
  for (int nt = 0; nt < 2; ++nt) {
    const u16* krow = kbase + (size_t)(klo + nt * 16 + nl) * E_;
    bk[nt][0] = *(const bf16x8*)(krow + q8 * 8);
    bk[nt][1] = *(const bf16x8*)(krow + 32 + q8 * 8);
  }

  for (int kt = klo; kt < khi; kt += 32) {
    bf16x8 bv[4];
#pragma unroll
    for (int dt = 0; dt < 4; ++dt)
      bv[dt] = *(const bf16x8*)(vbase + (size_t)(dt * 16 + nl) * T_ + kt + q8 * 8);

    int ktn = (kt + 32 < khi) ? kt + 32 : kt;
    bf16x8 nbk[2][2];
#pragma unroll
    for (int nt = 0; nt < 2; ++nt) {
      const u16* krow = kbase + (size_t)(ktn + nt * 16 + nl) * E_;
      nbk[nt][0] = *(const bf16x8*)(krow + q8 * 8);
      nbk[nt][1] = *(const bf16x8*)(krow + 32 + q8 * 8);
    }

    f32x4 sc[2][2] = {};
#pragma unroll
    for (int nt = 0; nt < 2; ++nt)
#pragma unroll
      for (int mt = 0; mt < 2; ++mt) {
        sc[mt][nt] = __builtin_amdgcn_mfma_f32_16x16x32_bf16(aq[mt][0], bk[nt][0], sc[mt][nt], 0, 0, 0);
        sc[mt][nt] = __builtin_amdgcn_mfma_f32_16x16x32_bf16(aq[mt][1], bk[nt][1], sc[mt][nt], 0, 0, 0);
      }

    if (kt < qw - 225 || kt > qw + 225) {
#pragma unroll
      for (int mt = 0; mt < 2; ++mt)
#pragma unroll
        for (int nt = 0; nt < 2; ++nt)
#pragma unroll
          for (int r = 0; r < 4; ++r) {
            int qa = qw + mt * 16 + q8 * 4 + r;
            int ka = kt + nt * 16 + nl;
            int d = ka - qa;
            sc[mt][nt][r] = (d < -WIN_ || d > WIN_) ? -1e30f : sc[mt][nt][r];
          }
    }

#pragma unroll
    for (int mt = 0; mt < 2; ++mt)
#pragma unroll
      for (int r = 0; r < 4; ++r) {
        float p0 = exp2f(sc[mt][0][r]);
        float p1 = exp2f(sc[mt][1][r]);
        sc[mt][0][r] = p0; sc[mt][1][r] = p1;
        lacc[mt][r] += p0 + p1;
      }

#pragma unroll
    for (int mt = 0; mt < 2; ++mt)
#pragma unroll
      for (int r = 0; r < 4; ++r) {
        Pl[wave][mt][q8 * 4 + r][nl] = f2bf(sc[mt][0][r]);
        Pl[wave][mt][q8 * 4 + r][16 + nl] = f2bf(sc[mt][1][r]);
      }

    bf16x8 ap[2];
#pragma unroll
    for (int mt = 0; mt < 2; ++mt) {
      bf16x4 lo = *(const bf16x4*)&Pl[wave][mt][nl][q8 * 8];
      bf16x4 hi = *(const bf16x4*)&Pl[wave][mt][nl][q8 * 8 + 4];
      bf16x8 a;
      a[0] = lo[0]; a[1] = lo[1]; a[2] = lo[2]; a[3] = lo[3];
      a[4] = hi[0]; a[5] = hi[1]; a[6] = hi[2]; a[7] = hi[3];
      ap[mt] = a;
    }

#pragma unroll
    for (int dt = 0; dt < 4; ++dt)
#pragma unroll
      for (int mt = 0; mt < 2; ++mt)
        O[mt][dt] = __builtin_amdgcn_mfma_f32_16x16x32_bf16(ap[mt], bv[dt], O[mt][dt], 0, 0, 0);

#pragma unroll
    for (int nt = 0; nt < 2; ++nt) {
      bk[nt][0] = nbk[nt][0];
      bk[nt][1] = nbk[nt][1];
    }
  }

#pragma unroll
  for (int mt = 0; mt < 2; ++mt)
#pragma unroll
    for (int r = 0; r < 4; ++r) {
      float l = lacc[mt][r];
      l += __shfl_xor(l, 1); l += __shfl_xor(l, 2);
      l += __shfl_xor(l, 4); l += __shfl_xor(l, 8);
      float inv = 1.0f / l;
      int qa = qw + mt * 16 + q8 * 4 + r;
      float* op = out + (size_t)(b * T_ + qa) * E_ + ho;
#pragma unroll
      for (int dt = 0; dt < 4; ++dt)
        op[dt * 16 + nl] = O[mt][dt][r] * inv;
    }
}

extern "C" void kernel_launch(void* const* d_in, const int* in_sizes, int n_in,
                              void* d_out, int out_size, void* d_ws, size_t ws_size,
                              hipStream_t stream) {
  const float* x  = (const float*)d_in[0];
  const float* Wq = (const float*)d_in[1];
  const float* Wk = (const float*)d_in[2];
  const float* Wv = (const float*)d_in[3];
  float* out = (float*)d_out;

  const size_t M = (size_t)B_ * T_;
  u16* xb  = (u16*)d_ws;               // M*E bf16; reused as vT after gemm
  u16* wb  = xb + M * E_;              // 3*E*E
  u16* qkv = wb + 3 * (size_t)E_ * E_; // 3*M*E
  u16* vT  = xb;                       // [B][E][T]

  const int n4x = B_ * T_ * E_ / 4;
  const int n4w = E_ * E_ / 4;
  int cvt_blocks = (n4x + 3 * n4w + 255) / 256;
  cvt_all<<<cvt_blocks, 256, 0, stream>>>(x, Wq, Wk, Wv, xb, wb);

  dim3 g1(M / 256, E_ / 64, 3);
  gemm_qkv<<<g1, 256, 0, stream>>>(xb, wb, qkv);

  dim3 gt(T_ / 64, E_ / 64, B_);
  transpose_v<<<gt, 256, 0, stream>>>(qkv + 2 * M * E_, vT);

  dim3 g2(T_ / 128, B_ * H_);
  attn_kernel<<<g2, 256, 0, stream>>>(qkv, vT, out);
}

// Round 5
// 211.543 us; speedup vs baseline: 1.2167x; 1.2167x over previous
//
#include <hip/hip_runtime.h>

#define B_ 2
#define T_ 4096
#define E_ 768
#define H_ 12
#define S_ 64
#define WIN_ 256

typedef unsigned short u16;
typedef unsigned int u32;
typedef __attribute__((ext_vector_type(8))) short bf16x8;
typedef __attribute__((ext_vector_type(4))) short bf16x4;
typedef __attribute__((ext_vector_type(4))) float f32x4;

__device__ __forceinline__ u16 f2bf(float f) {
  u32 u = __float_as_uint(f);
  u += ((u >> 16) & 1u) + 0x7fffu;   // RNE
  return (u16)(u >> 16);
}

__device__ __forceinline__ void async_copy16(const u16* g, u16* l) {
  __builtin_amdgcn_global_load_lds(
      (const __attribute__((address_space(1))) void*)g,
      (__attribute__((address_space(3))) void*)l, 16, 0, 0);
}

// ---------------- fp32 -> bf16, all 4 tensors in one dispatch ----------------
__global__ void cvt_all(const float* __restrict__ x, const float* __restrict__ wq,
                        const float* __restrict__ wk, const float* __restrict__ wv,
                        u16* __restrict__ xb, u16* __restrict__ wb) {
  const int n4x = B_ * T_ * E_ / 4;
  const int n4w = E_ * E_ / 4;
  int i = blockIdx.x * 256 + threadIdx.x;
  const float* src;
  u16* dst;
  int j;
  if (i < n4x) {
    src = x; dst = xb; j = i;
  } else {
    int t = i - n4x;
    int z = t / n4w;
    if (z >= 3) return;
    j = t - z * n4w;
    src = (z == 0) ? wq : ((z == 1) ? wk : wv);
    dst = wb + (size_t)z * E_ * E_;
  }
  float4 v = ((const float4*)src)[j];
  ushort4 o;
  o.x = f2bf(v.x); o.y = f2bf(v.y); o.z = f2bf(v.z); o.w = f2bf(v.w);
  ((ushort4*)dst)[j] = o;
}

// ---------------- QKV projection GEMM: 3-stage pipeline, raw s_barrier + vmcnt(4) ----------------
// Stage k+2 issued after barrier k; s_waitcnt vmcnt(4) drains only stage k
// (oldest 4 of 8 outstanding) so k+1/k+2 stay in flight across the barrier.
__global__ __launch_bounds__(256)
void gemm_qkv(const u16* __restrict__ xb, const u16* __restrict__ wb,
              u16* __restrict__ qkv) {
  const int M = B_ * T_;
  __shared__ u16 As[3][4][128][8];   // 3 stages x 8KB
  __shared__ u16 Bs[3][4][128][8];   // total 48KB -> 3 blocks/CU
  int tid = threadIdx.x;
  int lane = tid & 63, wave = tid >> 6;
  int wr = wave >> 1, wc = wave & 1;
  int q8 = lane >> 4, nl = lane & 15;
  int bm = blockIdx.x * 128, bn = blockIdx.y * 128;
  int z = blockIdx.z;
  const u16* A = xb;
  const u16* Bmat = wb + (size_t)z * E_ * E_;
  u16* C = qkv + (size_t)z * M * E_;
  float scale = (z == 0) ? (0.125f * 1.44269504088896f) : 1.0f;

  int ch0 = tid >> 7, row0 = tid & 127;
  int u1 = tid + 256;
  int ch1 = u1 >> 7, row1 = u1 & 127;
  const u16* ga0 = A + (size_t)(bm + row0) * E_ + ch0 * 8;
  const u16* ga1 = A + (size_t)(bm + row1) * E_ + ch1 * 8;
  const u16* gb0 = Bmat + (size_t)(bn + row0) * E_ + ch0 * 8;
  const u16* gb1 = Bmat + (size_t)(bn + row1) * E_ + ch1 * 8;

  const int NK = E_ / 32;   // 24

#define STAGE(s, ko)                                   \
  do {                                                 \
    async_copy16(ga0 + (ko), &As[s][ch0][row0][0]);    \
    async_copy16(ga1 + (ko), &As[s][ch1][row1][0]);    \
    async_copy16(gb0 + (ko), &Bs[s][ch0][row0][0]);    \
    async_copy16(gb1 + (ko), &Bs[s][ch1][row1][0]);    \
  } while (0)

  STAGE(0, 0);
  STAGE(1, 32);

  f32x4 acc[4][4] = {};

#define COMPUTE(cur)                                                                          \
  do {                                                                                        \
    bf16x8 af[4], bfr[4];                                                                     \
    _Pragma("unroll") for (int i = 0; i < 4; ++i)                                             \
        af[i] = *(const bf16x8*)&As[cur][q8][wr * 64 + i * 16 + nl][0];                       \
    _Pragma("unroll") for (int i = 0; i < 4; ++i)                                             \
        bfr[i] = *(const bf16x8*)&Bs[cur][q8][wc * 64 + i * 16 + nl][0];                      \
    _Pragma("unroll") for (int i = 0; i < 4; ++i)                                             \
        _Pragma("unroll") for (int j2 = 0; j2 < 4; ++j2)                                      \
            acc[i][j2] = __builtin_amdgcn_mfma_f32_16x16x32_bf16(af[i], bfr[j2], acc[i][j2], 0, 0, 0); \
  } while (0)

  for (int ki = 0; ki < NK - 1; ++ki) {
    int cur = ki % 3;
    // wait for stage ki only: 8 outstanding (ki, ki+1) -> leave 4 (ki+1)
    asm volatile("s_waitcnt vmcnt(4)" ::: "memory");
    __builtin_amdgcn_s_barrier();
    asm volatile("" ::: "memory");
    if (ki + 2 < NK) {
      int s2 = (ki + 2) % 3;
      int ko = (ki + 2) * 32;
      STAGE(s2, ko);
    }
    COMPUTE(cur);
  }
  // final iteration: only stage NK-1 outstanding -> full drain
  asm volatile("s_waitcnt vmcnt(0)" ::: "memory");
  __builtin_amdgcn_s_barrier();
  asm volatile("" ::: "memory");
  COMPUTE((NK - 1) % 3);

#pragma unroll
  for (int i = 0; i < 4; ++i)
#pragma unroll
    for (int j2 = 0; j2 < 4; ++j2)
#pragma unroll
      for (int r = 0; r < 4; ++r) {
        int row = bm + wr * 64 + i * 16 + q8 * 4 + r;
        int col = bn + wc * 64 + j2 * 16 + nl;
        C[(size_t)row * E_ + col] = f2bf(acc[i][j2][r] * scale);
      }
#undef STAGE
#undef COMPUTE
}

// ---------------- V transpose: v[b*T+t][e] -> vT[b][e][t] ----------------
__global__ void transpose_v(const u16* __restrict__ v, u16* __restrict__ vT) {
  __shared__ u16 lt[64][66];
  int t = threadIdx.x;
  int t0 = blockIdx.x * 64;
  int e0 = blockIdx.y * 64;
  int b = blockIdx.z;
#pragma unroll
  for (int i = 0; i < 2; ++i) {
    int u = t + i * 256;
    int tok = u >> 3, cg = u & 7;
    bf16x8 val = *(const bf16x8*)(v + (size_t)(b * T_ + t0 + tok) * E_ + e0 + cg * 8);
#pragma unroll
    for (int j = 0; j < 8; ++j) lt[tok][cg * 8 + j] = (u16)val[j];
  }
  __syncthreads();
#pragma unroll
  for (int i = 0; i < 2; ++i) {
    int u = t + i * 256;
    int d = u >> 3, ck = u & 7;
    bf16x8 o;
#pragma unroll
    for (int j = 0; j < 8; ++j) o[j] = (short)lt[ck * 8 + j][d];
    *(bf16x8*)(vT + (size_t)(b * E_ + e0 + d) * T_ + t0 + ck * 8) = o;
  }
}

// ---------------- banded flash attention, barrier-free + register prefetch ----------------
__global__ __launch_bounds__(256)
void attn_kernel(const u16* __restrict__ qkv, const u16* __restrict__ vT,
                 float* __restrict__ out) {
  const int Mtot = B_ * T_;
  const u16* qb = qkv;
  const u16* kb = qkv + (size_t)Mtot * E_;

  __shared__ u16 Pl[4][2][16][36];

  int tid = threadIdx.x;
  int lane = tid & 63, wave = tid >> 6;
  int q8 = lane >> 4, nl = lane & 15;
  int qs = blockIdx.x * 128;
  int bh = blockIdx.y;
  int b = bh / H_, h = bh % H_;
  int qw = qs + wave * 32;
  size_t ho = (size_t)h * S_;

  bf16x8 aq[2][2];
#pragma unroll
  for (int mt = 0; mt < 2; ++mt) {
    const u16* qrow = qb + (size_t)(b * T_ + qw + mt * 16 + nl) * E_ + ho;
    aq[mt][0] = *(const bf16x8*)(qrow + q8 * 8);
    aq[mt][1] = *(const bf16x8*)(qrow + 32 + q8 * 8);
  }

  f32x4 O[2][4] = {};
  f32x4 lacc[2] = {};

  int klo = qw - WIN_; if (klo < 0) klo = 0;
  int khi = qw + 32 + WIN_; if (khi > T_) khi = T_;

  const u16* kbase = kb + (size_t)b * T_ * E_ + ho;
  const u16* vbase = vT + (size_t)b * E_ * T_ + ho * T_;

  bf16x8 bk[2][2];
#pragma unroll
  for (int nt = 0; nt < 2; ++nt) {
    const u16* krow = kbase + (size_t)(klo + nt * 16 + nl) * E_;
    bk[nt][0] = *(const bf16x8*)(krow + q8 * 8);
    bk[nt][1] = *(const bf16x8*)(krow + 32 + q8 * 8);
  }

  for (int kt = klo; kt < khi; kt += 32) {
    bf16x8 bv[4];
#pragma unroll
    for (int dt = 0; dt < 4; ++dt)
      bv[dt] = *(const bf16x8*)(vbase + (size_t)(dt * 16 + nl) * T_ + kt + q8 * 8);

    int ktn = (kt + 32 < khi) ? kt + 32 : kt;
    bf16x8 nbk[2][2];
#pragma unroll
    for (int nt = 0; nt < 2; ++nt) {
      const u16* krow = kbase + (size_t)(ktn + nt * 16 + nl) * E_;
      nbk[nt][0] = *(const bf16x8*)(krow + q8 * 8);
      nbk[nt][1] = *(const bf16x8*)(krow + 32 + q8 * 8);
    }

    f32x4 sc[2][2] = {};
#pragma unroll
    for (int nt = 0; nt < 2; ++nt)
#pragma unroll
      for (int mt = 0; mt < 2; ++mt) {
        sc[mt][nt] = __builtin_amdgcn_mfma_f32_16x16x32_bf16(aq[mt][0], bk[nt][0], sc[mt][nt], 0, 0, 0);
        sc[mt][nt] = __builtin_amdgcn_mfma_f32_16x16x32_bf16(aq[mt][1], bk[nt][1], sc[mt][nt], 0, 0, 0);
      }

    if (kt < qw - 225 || kt > qw + 225) {
#pragma unroll
      for (int mt = 0; mt < 2; ++mt)
#pragma unroll
        for (int nt = 0; nt < 2; ++nt)
#pragma unroll
          for (int r = 0; r < 4; ++r) {
            int qa = qw + mt * 16 + q8 * 4 + r;
            int ka = kt + nt * 16 + nl;
            int d = ka - qa;
            sc[mt][nt][r] = (d < -WIN_ || d > WIN_) ? -1e30f : sc[mt][nt][r];
          }
    }

#pragma unroll
    for (int mt = 0; mt < 2; ++mt)
#pragma unroll
      for (int r = 0; r < 4; ++r) {
        float p0 = exp2f(sc[mt][0][r]);
        float p1 = exp2f(sc[mt][1][r]);
        sc[mt][0][r] = p0; sc[mt][1][r] = p1;
        lacc[mt][r] += p0 + p1;
      }

#pragma unroll
    for (int mt = 0; mt < 2; ++mt)
#pragma unroll
      for (int r = 0; r < 4; ++r) {
        Pl[wave][mt][q8 * 4 + r][nl] = f2bf(sc[mt][0][r]);
        Pl[wave][mt][q8 * 4 + r][16 + nl] = f2bf(sc[mt][1][r]);
      }

    bf16x8 ap[2];
#pragma unroll
    for (int mt = 0; mt < 2; ++mt) {
      bf16x4 lo = *(const bf16x4*)&Pl[wave][mt][nl][q8 * 8];
      bf16x4 hi = *(const bf16x4*)&Pl[wave][mt][nl][q8 * 8 + 4];
      bf16x8 a;
      a[0] = lo[0]; a[1] = lo[1]; a[2] = lo[2]; a[3] = lo[3];
      a[4] = hi[0]; a[5] = hi[1]; a[6] = hi[2]; a[7] = hi[3];
      ap[mt] = a;
    }

#pragma unroll
    for (int dt = 0; dt < 4; ++dt)
#pragma unroll
      for (int mt = 0; mt < 2; ++mt)
        O[mt][dt] = __builtin_amdgcn_mfma_f32_16x16x32_bf16(ap[mt], bv[dt], O[mt][dt], 0, 0, 0);

#pragma unroll
    for (int nt = 0; nt < 2; ++nt) {
      bk[nt][0] = nbk[nt][0];
      bk[nt][1] = nbk[nt][1];
    }
  }

#pragma unroll
  for (int mt = 0; mt < 2; ++mt)
#pragma unroll
    for (int r = 0; r < 4; ++r) {
      float l = lacc[mt][r];
      l += __shfl_xor(l, 1); l += __shfl_xor(l, 2);
      l += __shfl_xor(l, 4); l += __shfl_xor(l, 8);
      float inv = 1.0f / l;
      int qa = qw + mt * 16 + q8 * 4 + r;
      float* op = out + (size_t)(b * T_ + qa) * E_ + ho;
#pragma unroll
      for (int dt = 0; dt < 4; ++dt)
        op[dt * 16 + nl] = O[mt][dt][r] * inv;
    }
}

extern "C" void kernel_launch(void* const* d_in, const int* in_sizes, int n_in,
                              void* d_out, int out_size, void* d_ws, size_t ws_size,
                              hipStream_t stream) {
  const float* x  = (const float*)d_in[0];
  const float* Wq = (const float*)d_in[1];
  const float* Wk = (const float*)d_in[2];
  const float* Wv = (const float*)d_in[3];
  float* out = (float*)d_out;

  const size_t M = (size_t)B_ * T_;
  u16* xb  = (u16*)d_ws;               // M*E bf16; reused as vT after gemm
  u16* wb  = xb + M * E_;              // 3*E*E
  u16* qkv = wb + 3 * (size_t)E_ * E_; // 3*M*E
  u16* vT  = xb;                       // [B][E][T]

  const int n4x = B_ * T_ * E_ / 4;
  const int n4w = E_ * E_ / 4;
  int cvt_blocks = (n4x + 3 * n4w + 255) / 256;
  cvt_all<<<cvt_blocks, 256, 0, stream>>>(x, Wq, Wk, Wv, xb, wb);

  dim3 g1(M / 128, E_ / 128, 3);
  gemm_qkv<<<g1, 256, 0, stream>>>(xb, wb, qkv);

  dim3 gt(T_ / 64, E_ / 64, B_);
  transpose_v<<<gt, 256, 0, stream>>>(qkv + 2 * M * E_, vT);

  dim3 g2(T_ / 128, B_ * H_);
  attn_kernel<<<g2, 256, 0, stream>>>(qkv, vT, out);
}